// Round 1
// baseline (2078.458 us; speedup 1.0000x reference)
//
#include <hip/hip_runtime.h>
#include <stdint.h>

// ============================================================================
// StrategyAwareStringScalarOps — fused bf16-MFMA implementation.
//
// Pipeline (3 launches on `stream`):
//   k_prep   : top-4 of 120 pair scores + softmax weights + (ti,tj) indices
//              (block 0, thread 0, exact f32) ; blocks 1..480 repack the six
//              weight matrices f32 -> bf16 in B-fragment-native layout
//              [ct][kk][lane][8] so B-frag loads are coalesced dwordx4.
//   k_gather : writes s-gather, c-gather, s*c (f32 product, RNE to bf16) in
//              A-fragment-native layout [tile16][kk][lane][8].
//   k_main   : 1 block = 32 rows (8 batches x 4 topk slots), 4 waves.
//              Chain of 6 GEMMs through 64KB LDS, f32 accum, fused
//              bias/relu, LayerNorm, and in-lane weighted sum over k.
//
// MFMA v_mfma_f32_16x16x32_bf16 layouts (HW-verified per guide):
//   A: lane holds A[m=lane&15][k=(lane>>4)*8+j]
//   B: lane holds B[k=(lane>>4)*8+j][n=lane&15]
//   D: lane holds D[row=(lane>>4)*4+r][col=lane&15]
// ============================================================================

typedef __attribute__((ext_vector_type(8))) short frag8;   // 8 x bf16
typedef __attribute__((ext_vector_type(4))) float f4;
typedef __attribute__((ext_vector_type(4))) int   i4;

#define MFMA16(a,b,c) __builtin_amdgcn_mfma_f32_16x16x32_bf16((a),(b),(c),0,0,0)

__device__ __forceinline__ short f2bf(float x) {            // RNE f32 -> bf16
  unsigned u = __float_as_uint(x);
  return (short)((u + 0x7FFFu + ((u >> 16) & 1u)) >> 16);
}
__device__ __forceinline__ float bf2f(short s) {
  return __uint_as_float(((unsigned)(unsigned short)s) << 16);
}
__device__ __forceinline__ frag8 ldg8(const short* __restrict__ p) {
  return *reinterpret_cast<const frag8*>(p);
}

// ---------------------------------------------------------------------------
// Workspace layout (bytes):
//   0        : float wts[4] ; int ti[4] @ 16 ; int tj[4] @ 32
//   256      : w1p  (768x256 bf16)   393216
//   393472   : w2p  (256x256)        131072
//   524544   : dw1p (512x256)        262144
//   786688   : dw2p (256x256)        131072
//   917760   : fw1p (768x512)        786432
//   1704192  : fw2p (512x256)        262144
//   2097152  : sg  (131072x256 bf16) 67108864
//   69206016 : cg                    67108864
//   136314880: pg                    67108864    (end: 203423744 ~ 194 MiB)
// ---------------------------------------------------------------------------

__global__ __launch_bounds__(256) void k_prep(
    const float* __restrict__ ps, const float* __restrict__ tempp,
    const float* __restrict__ w1, const float* __restrict__ w2,
    const float* __restrict__ dw1, const float* __restrict__ dw2,
    const float* __restrict__ fw1, const float* __restrict__ fw2,
    short* __restrict__ w1p, short* __restrict__ w2p,
    short* __restrict__ dw1p, short* __restrict__ dw2p,
    short* __restrict__ fw1p, short* __restrict__ fw2p,
    float* __restrict__ hdrf, int* __restrict__ hdri)
{
  if (blockIdx.x == 0) {
    if (threadIdx.x == 0) {
      // top-4 of the 6x20 scores; strict '>' keeps earliest index (lax.top_k)
      float tv[4]; int bi[4];
      bool used[120];
      for (int i = 0; i < 120; ++i) used[i] = false;
      for (int t = 0; t < 4; ++t) {
        float bv = -3.4e38f; int bb = 0;
        for (int i = 0; i < 120; ++i) {
          if (!used[i] && ps[i] > bv) { bv = ps[i]; bb = i; }
        }
        used[bb] = true; tv[t] = bv; bi[t] = bb;
      }
      float tmp = fmaxf(tempp[0], 0.1f);
      float mx = tv[0];
      float e[4], s = 0.f;
      for (int t = 0; t < 4; ++t) { e[t] = expf((tv[t] - mx) / tmp); s += e[t]; }
      for (int t = 0; t < 4; ++t) {
        hdrf[t]     = e[t] / s;
        hdri[4 + t] = bi[t] / 20;   // ti
        hdri[8 + t] = bi[t] % 20;   // tj
      }
    }
    return;
  }
  // ---- weight repack: one thread = one 16B B-fragment (8 elems) ----
  int u = (blockIdx.x - 1) * 256 + threadIdx.x;   // 0 .. 122879
  const float* W; short* O; int N, KK;
  if      (u < 24576) {             W = w1;  O = w1p;  N = 256; KK = 24; }
  else if (u < 32768) { u -= 24576; W = w2;  O = w2p;  N = 256; KK = 8;  }
  else if (u < 49152) { u -= 32768; W = dw1; O = dw1p; N = 256; KK = 16; }
  else if (u < 57344) { u -= 49152; W = dw2; O = dw2p; N = 256; KK = 8;  }
  else if (u < 106496){ u -= 57344; W = fw1; O = fw1p; N = 512; KK = 24; }
  else                { u -= 106496;W = fw2; O = fw2p; N = 256; KK = 16; }
  int lane = u & 63, rest = u >> 6;
  int kk = rest % KK, ct = rest / KK;
  int k0 = kk * 32 + (lane >> 4) * 8;
  int n  = ct * 16 + (lane & 15);
  frag8 f;
  #pragma unroll
  for (int j = 0; j < 8; ++j) f[j] = f2bf(W[(size_t)(k0 + j) * N + n]);
  *reinterpret_cast<frag8*>(O + (size_t)u * 8) = f;
}

__global__ __launch_bounds__(256) void k_gather(
    const float* __restrict__ sEnc, const float* __restrict__ cEnc,
    const int* __restrict__ hdri,
    short* __restrict__ sg, short* __restrict__ cg, short* __restrict__ pg)
{
  // one thread = one 16B A-fragment for each of sg/cg/pg
  int g = blockIdx.x * 256 + threadIdx.x;        // 0 .. 4194303
  int lane = g & 63, rest = g >> 6;
  int kk = rest & 7, t16 = rest >> 3;            // t16 = 16-row tile index
  int p = t16 * 16 + (lane & 15);                // row = b*4 + slot
  int b = p >> 2, slot = p & 3;
  int k0 = kk * 32 + (lane >> 4) * 8;
  int ti = hdri[4 + slot], tj = hdri[8 + slot];
  const float* sp = sEnc + ((size_t)b * 6  + ti) * 256 + k0;
  const float* cp = cEnc + ((size_t)b * 20 + tj) * 256 + k0;
  f4 sA = *(const f4*)sp;  f4 sB = *(const f4*)(sp + 4);
  f4 cA = *(const f4*)cp;  f4 cB = *(const f4*)(cp + 4);
  frag8 fs, fc, fp;
  #pragma unroll
  for (int j = 0; j < 8; ++j) {
    float sv = (j < 4) ? sA[j] : sB[j - 4];
    float cv = (j < 4) ? cA[j] : cB[j - 4];
    fs[j] = f2bf(sv); fc[j] = f2bf(cv); fp[j] = f2bf(sv * cv);
  }
  size_t off = (size_t)g * 8;
  *reinterpret_cast<frag8*>(sg + off) = fs;
  *reinterpret_cast<frag8*>(cg + off) = fc;
  *reinterpret_cast<frag8*>(pg + off) = fp;
}

// epilogue for N=256 GEMMs: bias (+relu) then store bf16 into LDS [32][stride]
__device__ __forceinline__ void epi4(const f4 (&acc)[2][4],
                                     const float* __restrict__ bias, bool relu,
                                     short* __restrict__ dst, int stride,
                                     int wv, int m15, int q)
{
  #pragma unroll
  for (int c = 0; c < 4; ++c) {
    int col = wv * 64 + c * 16 + m15;
    float bv = bias[col];
    #pragma unroll
    for (int t = 0; t < 2; ++t) {
      #pragma unroll
      for (int r = 0; r < 4; ++r) {
        float x = acc[t][c][r] + bv;
        if (relu) x = fmaxf(x, 0.f);
        dst[(t * 16 + q * 4 + r) * stride + col] = f2bf(x);
      }
    }
  }
}

__global__ __launch_bounds__(256, 2) void k_main(
    const short* __restrict__ sg, const short* __restrict__ cg,
    const short* __restrict__ pg,
    const short* __restrict__ w1p,  const short* __restrict__ w2p,
    const short* __restrict__ dw1p, const short* __restrict__ dw2p,
    const short* __restrict__ fw1p, const short* __restrict__ fw2p,
    const float* __restrict__ cm_b1, const float* __restrict__ cm_b2,
    const float* __restrict__ df_b1, const float* __restrict__ df_b2,
    const float* __restrict__ fu_b1, const float* __restrict__ fu_b2,
    const float* __restrict__ ln_g,  const float* __restrict__ ln_b,
    const float* __restrict__ hdrf,  float* __restrict__ out)
{
  __shared__ short sCF[32 * 256];   // 16KB  cross_f  (later: LN reduce buf)
  __shared__ short sDF[32 * 256];   // 16KB  diff_f
  __shared__ short sXY[32 * 512];   // 32KB  X1/X2 (first half) then Y

  const int tid  = threadIdx.x;
  const int wv   = tid >> 6;        // wave 0..3 -> col strip
  const int lane = tid & 63;
  const int m15  = lane & 15;
  const int q    = lane >> 4;
  const int blk  = blockIdx.x;
  const int t0   = blk * 2, t1 = blk * 2 + 1;   // global 16-row tile indices
  const f4 fz = {0.f, 0.f, 0.f, 0.f};

  // ---------------- GEMM1: X1 = relu([s|c|s*c] @ cm_w1 + b1) ----------------
  {
    f4 acc[2][4];
    #pragma unroll
    for (int t = 0; t < 2; ++t) {
      #pragma unroll
      for (int c = 0; c < 4; ++c) acc[t][c] = fz;
    }
    auto seg = [&](const short* __restrict__ A, int kb) {
      #pragma unroll
      for (int kk = 0; kk < 8; ++kk) {
        frag8 a0 = ldg8(A + ((size_t)(t0 * 8 + kk) * 64 + lane) * 8);
        frag8 a1 = ldg8(A + ((size_t)(t1 * 8 + kk) * 64 + lane) * 8);
        #pragma unroll
        for (int c = 0; c < 4; ++c) {
          frag8 b = ldg8(w1p + ((size_t)((wv * 4 + c) * 24 + kb + kk) * 64 + lane) * 8);
          acc[0][c] = MFMA16(a0, b, acc[0][c]);
          acc[1][c] = MFMA16(a1, b, acc[1][c]);
        }
      }
    };
    seg(sg, 0); seg(cg, 8); seg(pg, 16);
    epi4(acc, cm_b1, true, sXY, 256, wv, m15, q);
  }
  __syncthreads();

  // ---------------- GEMM2: cross_f = X1 @ cm_w2 + b2 ----------------
  {
    f4 acc[2][4];
    #pragma unroll
    for (int t = 0; t < 2; ++t) {
      #pragma unroll
      for (int c = 0; c < 4; ++c) acc[t][c] = fz;
    }
    #pragma unroll
    for (int kk = 0; kk < 8; ++kk) {
      frag8 a0 = *reinterpret_cast<const frag8*>(&sXY[(m15) * 256 + kk * 32 + q * 8]);
      frag8 a1 = *reinterpret_cast<const frag8*>(&sXY[(16 + m15) * 256 + kk * 32 + q * 8]);
      #pragma unroll
      for (int c = 0; c < 4; ++c) {
        frag8 b = ldg8(w2p + ((size_t)((wv * 4 + c) * 8 + kk) * 64 + lane) * 8);
        acc[0][c] = MFMA16(a0, b, acc[0][c]);
        acc[1][c] = MFMA16(a1, b, acc[1][c]);
      }
    }
    epi4(acc, cm_b2, false, sCF, 256, wv, m15, q);
  }
  __syncthreads();

  // ---------- GEMMd1: X2 = relu([d | |d|] @ df_w1 + b1), d = s - c ----------
  {
    f4 acc[2][4];
    #pragma unroll
    for (int t = 0; t < 2; ++t) {
      #pragma unroll
      for (int c = 0; c < 4; ++c) acc[t][c] = fz;
    }
    #pragma unroll
    for (int kk = 0; kk < 8; ++kk) {
      frag8 s0 = ldg8(sg + ((size_t)(t0 * 8 + kk) * 64 + lane) * 8);
      frag8 s1 = ldg8(sg + ((size_t)(t1 * 8 + kk) * 64 + lane) * 8);
      frag8 c0 = ldg8(cg + ((size_t)(t0 * 8 + kk) * 64 + lane) * 8);
      frag8 c1 = ldg8(cg + ((size_t)(t1 * 8 + kk) * 64 + lane) * 8);
      frag8 d0, d1;
      #pragma unroll
      for (int j = 0; j < 8; ++j) {
        d0[j] = f2bf(bf2f(s0[j]) - bf2f(c0[j]));
        d1[j] = f2bf(bf2f(s1[j]) - bf2f(c1[j]));
      }
      i4 ai0 = __builtin_bit_cast(i4, d0);
      i4 ai1 = __builtin_bit_cast(i4, d1);
      #pragma unroll
      for (int jj = 0; jj < 4; ++jj) { ai0[jj] &= 0x7FFF7FFF; ai1[jj] &= 0x7FFF7FFF; }
      frag8 e0 = __builtin_bit_cast(frag8, ai0);   // |d| : sign-bit clear
      frag8 e1 = __builtin_bit_cast(frag8, ai1);
      #pragma unroll
      for (int c = 0; c < 4; ++c) {
        frag8 b0 = ldg8(dw1p + ((size_t)((wv * 4 + c) * 16 + kk) * 64 + lane) * 8);
        acc[0][c] = MFMA16(d0, b0, acc[0][c]);
        acc[1][c] = MFMA16(d1, b0, acc[1][c]);
        frag8 b1 = ldg8(dw1p + ((size_t)((wv * 4 + c) * 16 + 8 + kk) * 64 + lane) * 8);
        acc[0][c] = MFMA16(e0, b1, acc[0][c]);
        acc[1][c] = MFMA16(e1, b1, acc[1][c]);
      }
    }
    epi4(acc, df_b1, true, sXY, 256, wv, m15, q);
  }
  __syncthreads();

  // ---------------- GEMMd2: diff_f = X2 @ df_w2 + b2 ----------------
  {
    f4 acc[2][4];
    #pragma unroll
    for (int t = 0; t < 2; ++t) {
      #pragma unroll
      for (int c = 0; c < 4; ++c) acc[t][c] = fz;
    }
    #pragma unroll
    for (int kk = 0; kk < 8; ++kk) {
      frag8 a0 = *reinterpret_cast<const frag8*>(&sXY[(m15) * 256 + kk * 32 + q * 8]);
      frag8 a1 = *reinterpret_cast<const frag8*>(&sXY[(16 + m15) * 256 + kk * 32 + q * 8]);
      #pragma unroll
      for (int c = 0; c < 4; ++c) {
        frag8 b = ldg8(dw2p + ((size_t)((wv * 4 + c) * 8 + kk) * 64 + lane) * 8);
        acc[0][c] = MFMA16(a0, b, acc[0][c]);
        acc[1][c] = MFMA16(a1, b, acc[1][c]);
      }
    }
    epi4(acc, df_b2, false, sDF, 256, wv, m15, q);
  }
  __syncthreads();

  // ------- GEMM3a: Y = relu([cross_f|diff_f|prod] @ fu_w1 + b1), N=512 -------
  {
    f4 acc[2][8];
    #pragma unroll
    for (int t = 0; t < 2; ++t) {
      #pragma unroll
      for (int c = 0; c < 8; ++c) acc[t][c] = fz;
    }
    auto segL = [&](const short* __restrict__ Abuf, int kb) {
      #pragma unroll
      for (int kk = 0; kk < 8; ++kk) {
        frag8 a0 = *reinterpret_cast<const frag8*>(&Abuf[(m15) * 256 + kk * 32 + q * 8]);
        frag8 a1 = *reinterpret_cast<const frag8*>(&Abuf[(16 + m15) * 256 + kk * 32 + q * 8]);
        #pragma unroll
        for (int c = 0; c < 8; ++c) {
          frag8 b = ldg8(fw1p + ((size_t)((wv * 8 + c) * 24 + kb + kk) * 64 + lane) * 8);
          acc[0][c] = MFMA16(a0, b, acc[0][c]);
          acc[1][c] = MFMA16(a1, b, acc[1][c]);
        }
      }
    };
    segL(sCF, 0); segL(sDF, 8);
    #pragma unroll
    for (int kk = 0; kk < 8; ++kk) {
      frag8 a0 = ldg8(pg + ((size_t)(t0 * 8 + kk) * 64 + lane) * 8);
      frag8 a1 = ldg8(pg + ((size_t)(t1 * 8 + kk) * 64 + lane) * 8);
      #pragma unroll
      for (int c = 0; c < 8; ++c) {
        frag8 b = ldg8(fw1p + ((size_t)((wv * 8 + c) * 24 + 16 + kk) * 64 + lane) * 8);
        acc[0][c] = MFMA16(a0, b, acc[0][c]);
        acc[1][c] = MFMA16(a1, b, acc[1][c]);
      }
    }
    #pragma unroll
    for (int c = 0; c < 8; ++c) {
      int col = wv * 128 + c * 16 + m15;
      float bv = fu_b1[col];
      #pragma unroll
      for (int t = 0; t < 2; ++t) {
        #pragma unroll
        for (int r = 0; r < 4; ++r) {
          float x = fmaxf(acc[t][c][r] + bv, 0.f);
          sXY[(t * 16 + q * 4 + r) * 512 + col] = f2bf(x);
        }
      }
    }
  }
  __syncthreads();

  // ------- GEMM3b: fused = Y @ fu_w2 + b2 ; LayerNorm ; weighted sum -------
  {
    f4 acc[2][4];
    #pragma unroll
    for (int t = 0; t < 2; ++t) {
      #pragma unroll
      for (int c = 0; c < 4; ++c) acc[t][c] = fz;
    }
    #pragma unroll
    for (int kk = 0; kk < 16; ++kk) {
      frag8 a0 = *reinterpret_cast<const frag8*>(&sXY[(m15) * 512 + kk * 32 + q * 8]);
      frag8 a1 = *reinterpret_cast<const frag8*>(&sXY[(16 + m15) * 512 + kk * 32 + q * 8]);
      #pragma unroll
      for (int c = 0; c < 4; ++c) {
        frag8 b = ldg8(fw2p + ((size_t)((wv * 4 + c) * 16 + kk) * 64 + lane) * 8);
        acc[0][c] = MFMA16(a0, b, acc[0][c]);
        acc[1][c] = MFMA16(a1, b, acc[1][c]);
      }
    }
    // fused values (f32): vals[t][c][r] at row = t*16 + q*4 + r, col = wv*64+c*16+m15
    float vals[2][4][4];
    #pragma unroll
    for (int c = 0; c < 4; ++c) {
      int col = wv * 64 + c * 16 + m15;
      float bv = fu_b2[col];
      #pragma unroll
      for (int t = 0; t < 2; ++t) {
        #pragma unroll
        for (int r = 0; r < 4; ++r) vals[t][c][r] = acc[t][c][r] + bv;
      }
    }
    // LN: per-row sum/sumsq — in-lane over c, shfl over 16 col-lanes, LDS over waves
    float s1v[2][4], s2v[2][4];
    #pragma unroll
    for (int t = 0; t < 2; ++t) {
      #pragma unroll
      for (int r = 0; r < 4; ++r) {
        float a = 0.f, b = 0.f;
        #pragma unroll
        for (int c = 0; c < 4; ++c) { float v = vals[t][c][r]; a += v; b += v * v; }
        s1v[t][r] = a; s2v[t][r] = b;
      }
    }
    #pragma unroll
    for (int off = 8; off >= 1; off >>= 1) {
      #pragma unroll
      for (int t = 0; t < 2; ++t) {
        #pragma unroll
        for (int r = 0; r < 4; ++r) {
          s1v[t][r] += __shfl_xor(s1v[t][r], off, 64);
          s2v[t][r] += __shfl_xor(s2v[t][r], off, 64);
        }
      }
    }
    float* red = reinterpret_cast<float*>(sCF);   // sCF dead after GEMM3a
    if (m15 == 0) {
      #pragma unroll
      for (int t = 0; t < 2; ++t) {
        #pragma unroll
        for (int r = 0; r < 4; ++r) {
          int row = t * 16 + q * 4 + r;
          red[(row * 4 + wv) * 2 + 0] = s1v[t][r];
          red[(row * 4 + wv) * 2 + 1] = s2v[t][r];
        }
      }
    }
    __syncthreads();
    float mu[2][4], rs[2][4];
    #pragma unroll
    for (int t = 0; t < 2; ++t) {
      #pragma unroll
      for (int r = 0; r < 4; ++r) {
        int row = t * 16 + q * 4 + r;
        float S1 = 0.f, S2 = 0.f;
        #pragma unroll
        for (int w = 0; w < 4; ++w) {
          S1 += red[(row * 4 + w) * 2];
          S2 += red[(row * 4 + w) * 2 + 1];
        }
        float m_ = S1 * (1.0f / 256.0f);
        float v_ = S2 * (1.0f / 256.0f) - m_ * m_;
        mu[t][r] = m_;
        rs[t][r] = rsqrtf(v_ + 1e-5f);
      }
    }
    // weighted sum over topk slots: rows 4g..4g+3 are regs r of one lane
    float wts[4] = {hdrf[0], hdrf[1], hdrf[2], hdrf[3]};
    #pragma unroll
    for (int c = 0; c < 4; ++c) {
      int col = wv * 64 + c * 16 + m15;
      float gv = ln_g[col], bv = ln_b[col];
      #pragma unroll
      for (int t = 0; t < 2; ++t) {
        float o = 0.f;
        #pragma unroll
        for (int r = 0; r < 4; ++r) {
          float rel = (vals[t][c][r] - mu[t][r]) * rs[t][r] * gv + bv;
          o += wts[r] * rel;
        }
        out[((size_t)(blk * 8 + t * 4 + q)) * 256 + col] = o;
      }
    }
  }
}

extern "C" void kernel_launch(void* const* d_in, const int* in_sizes, int n_in,
                              void* d_out, int out_size, void* d_ws, size_t ws_size,
                              hipStream_t stream)
{
  (void)in_sizes; (void)n_in; (void)out_size; (void)ws_size;
  const float* sEnc  = (const float*)d_in[0];
  const float* cEnc  = (const float*)d_in[1];
  const float* ps    = (const float*)d_in[2];
  const float* temp  = (const float*)d_in[3];
  const float* cm_w1 = (const float*)d_in[4];
  const float* cm_b1 = (const float*)d_in[5];
  const float* cm_w2 = (const float*)d_in[6];
  const float* cm_b2 = (const float*)d_in[7];
  const float* df_w1 = (const float*)d_in[8];
  const float* df_b1 = (const float*)d_in[9];
  const float* df_w2 = (const float*)d_in[10];
  const float* df_b2 = (const float*)d_in[11];
  const float* fu_w1 = (const float*)d_in[12];
  const float* fu_b1 = (const float*)d_in[13];
  const float* fu_w2 = (const float*)d_in[14];
  const float* fu_b2 = (const float*)d_in[15];
  const float* ln_g  = (const float*)d_in[16];
  const float* ln_b  = (const float*)d_in[17];

  char*  ws   = (char*)d_ws;
  float* hdrf = (float*)ws;
  int*   hdri = (int*)ws;
  short* w1p  = (short*)(ws + 256);
  short* w2p  = (short*)(ws + 393472);
  short* dw1p = (short*)(ws + 524544);
  short* dw2p = (short*)(ws + 786688);
  short* fw1p = (short*)(ws + 917760);
  short* fw2p = (short*)(ws + 1704192);
  short* sg   = (short*)(ws + 2097152);
  short* cg   = sg + (size_t)33554432;
  short* pg   = cg + (size_t)33554432;
  float* out  = (float*)d_out;

  k_prep<<<481, 256, 0, stream>>>(ps, temp, cm_w1, cm_w2, df_w1, df_w2, fu_w1, fu_w2,
                                  w1p, w2p, dw1p, dw2p, fw1p, fw2p, hdrf, hdri);
  k_gather<<<16384, 256, 0, stream>>>(sEnc, cEnc, (const int*)ws, sg, cg, pg);
  k_main<<<4096, 256, 0, stream>>>(sg, cg, pg, w1p, w2p, dw1p, dw2p, fw1p, fw2p,
                                   cm_b1, cm_b2, df_b1, df_b2, fu_b1, fu_b2,
                                   ln_g, ln_b, hdrf, out);
}

// Round 2
// 1481.061 us; speedup vs baseline: 1.4034x; 1.4034x over previous
//
#include <hip/hip_runtime.h>
#include <stdint.h>

// ============================================================================
// StrategyAwareStringScalarOps — fused bf16-MFMA implementation.
//
// Pipeline (3 launches on `stream`):
//   k_prep   : top-4 of 120 pair scores + softmax weights + (ti,tj) indices
//              (single-wave register top-k, butterfly shfl argmax) ; blocks
//              1..480 repack the six weight matrices f32 -> bf16 in
//              B-fragment-native layout [ct][kk][lane][8].
//   k_gather : writes s-gather, c-gather, s*c (f32 product, RNE to bf16) in
//              A-fragment-native layout [tile16][kk][lane][8].
//   k_main   : 1 block = 32 rows (8 batches x 4 topk slots), 4 waves.
//              Chain of 6 GEMMs through 64KB LDS, f32 accum, fused
//              bias/relu, LayerNorm, and in-lane weighted sum over k.
//
// R1 change: serial one-thread top-k (scratch-array + 480 dependent global
// loads -> 635us!) replaced by wave-parallel register top-k.
// ============================================================================

typedef __attribute__((ext_vector_type(8))) short frag8;   // 8 x bf16
typedef __attribute__((ext_vector_type(4))) float f4;
typedef __attribute__((ext_vector_type(4))) int   i4;

#define MFMA16(a,b,c) __builtin_amdgcn_mfma_f32_16x16x32_bf16((a),(b),(c),0,0,0)

__device__ __forceinline__ short f2bf(float x) {            // RNE f32 -> bf16
  unsigned u = __float_as_uint(x);
  return (short)((u + 0x7FFFu + ((u >> 16) & 1u)) >> 16);
}
__device__ __forceinline__ float bf2f(short s) {
  return __uint_as_float(((unsigned)(unsigned short)s) << 16);
}
__device__ __forceinline__ frag8 ldg8(const short* __restrict__ p) {
  return *reinterpret_cast<const frag8*>(p);
}

// ---------------------------------------------------------------------------
// Workspace layout (bytes):
//   0        : float wts[4] ; int ti[4] @ 16 ; int tj[4] @ 32
//   256      : w1p  (768x256 bf16)   393216
//   393472   : w2p  (256x256)        131072
//   524544   : dw1p (512x256)        262144
//   786688   : dw2p (256x256)        131072
//   917760   : fw1p (768x512)        786432
//   1704192  : fw2p (512x256)        262144
//   2097152  : sg  (131072x256 bf16) 67108864
//   69206016 : cg                    67108864
//   136314880: pg                    67108864    (end: 203423744 ~ 194 MiB)
// ---------------------------------------------------------------------------

__global__ __launch_bounds__(256) void k_prep(
    const float* __restrict__ ps, const float* __restrict__ tempp,
    const float* __restrict__ w1, const float* __restrict__ w2,
    const float* __restrict__ dw1, const float* __restrict__ dw2,
    const float* __restrict__ fw1, const float* __restrict__ fw2,
    short* __restrict__ w1p, short* __restrict__ w2p,
    short* __restrict__ dw1p, short* __restrict__ dw2p,
    short* __restrict__ fw1p, short* __restrict__ fw2p,
    float* __restrict__ hdrf, int* __restrict__ hdri)
{
  if (blockIdx.x == 0) {
    // ---- wave-parallel top-4 of 120 scores, all in registers ----
    const int lane = threadIdx.x;
    if (lane < 64) {
      const float NEG = -3.4e38f;
      float v0 = (lane < 120)      ? ps[lane]      : NEG;
      float v1 = (lane + 64 < 120) ? ps[lane + 64] : NEG;
      const int i0 = lane, i1 = lane + 64;
      unsigned elim = 0;
      float tv[4]; int bi[4];
      #pragma unroll
      for (int t = 0; t < 4; ++t) {
        float c0 = (elim & 1u) ? NEG : v0;
        float c1 = (elim & 2u) ? NEG : v1;
        float cv; int ci;
        if (c1 > c0) { cv = c1; ci = i1; } else { cv = c0; ci = i0; }
        #pragma unroll
        for (int off = 32; off >= 1; off >>= 1) {
          float ov = __shfl_xor(cv, off, 64);
          int   oi = __shfl_xor(ci, off, 64);
          if (ov > cv || (ov == cv && oi < ci)) { cv = ov; ci = oi; }
        }
        tv[t] = cv; bi[t] = ci;               // all lanes agree now
        if (ci == i0) elim |= 1u;
        if (ci == i1) elim |= 2u;
      }
      if (lane == 0) {
        float tmp = fmaxf(tempp[0], 0.1f);
        float mx = tv[0];
        float e[4], s = 0.f;
        #pragma unroll
        for (int t = 0; t < 4; ++t) { e[t] = __expf((tv[t] - mx) / tmp); s += e[t]; }
        #pragma unroll
        for (int t = 0; t < 4; ++t) {
          hdrf[t]     = e[t] / s;
          hdri[4 + t] = bi[t] / 20;   // ti
          hdri[8 + t] = bi[t] % 20;   // tj
        }
      }
    }
    return;
  }
  // ---- weight repack: one thread = one 16B B-fragment (8 elems) ----
  int u = (blockIdx.x - 1) * 256 + threadIdx.x;   // 0 .. 122879
  const float* W; short* O; int N, KK;
  if      (u < 24576) {             W = w1;  O = w1p;  N = 256; KK = 24; }
  else if (u < 32768) { u -= 24576; W = w2;  O = w2p;  N = 256; KK = 8;  }
  else if (u < 49152) { u -= 32768; W = dw1; O = dw1p; N = 256; KK = 16; }
  else if (u < 57344) { u -= 49152; W = dw2; O = dw2p; N = 256; KK = 8;  }
  else if (u < 106496){ u -= 57344; W = fw1; O = fw1p; N = 512; KK = 24; }
  else                { u -= 106496;W = fw2; O = fw2p; N = 256; KK = 16; }
  int lane = u & 63, rest = u >> 6;
  int kk = rest % KK, ct = rest / KK;
  int k0 = kk * 32 + (lane >> 4) * 8;
  int n  = ct * 16 + (lane & 15);
  frag8 f;
  #pragma unroll
  for (int j = 0; j < 8; ++j) f[j] = f2bf(W[(size_t)(k0 + j) * N + n]);
  *reinterpret_cast<frag8*>(O + (size_t)u * 8) = f;
}

__global__ __launch_bounds__(256) void k_gather(
    const float* __restrict__ sEnc, const float* __restrict__ cEnc,
    const int* __restrict__ hdri,
    short* __restrict__ sg, short* __restrict__ cg, short* __restrict__ pg)
{
  // one thread = one 16B A-fragment for each of sg/cg/pg
  int g = blockIdx.x * 256 + threadIdx.x;        // 0 .. 4194303
  int lane = g & 63, rest = g >> 6;
  int kk = rest & 7, t16 = rest >> 3;            // t16 = 16-row tile index
  int p = t16 * 16 + (lane & 15);                // row = b*4 + slot
  int b = p >> 2, slot = p & 3;
  int k0 = kk * 32 + (lane >> 4) * 8;
  int ti = hdri[4 + slot], tj = hdri[8 + slot];
  const float* sp = sEnc + ((size_t)b * 6  + ti) * 256 + k0;
  const float* cp = cEnc + ((size_t)b * 20 + tj) * 256 + k0;
  f4 sA = *(const f4*)sp;  f4 sB = *(const f4*)(sp + 4);
  f4 cA = *(const f4*)cp;  f4 cB = *(const f4*)(cp + 4);
  frag8 fs, fc, fp;
  #pragma unroll
  for (int j = 0; j < 8; ++j) {
    float sv = (j < 4) ? sA[j] : sB[j - 4];
    float cv = (j < 4) ? cA[j] : cB[j - 4];
    fs[j] = f2bf(sv); fc[j] = f2bf(cv); fp[j] = f2bf(sv * cv);
  }
  size_t off = (size_t)g * 8;
  *reinterpret_cast<frag8*>(sg + off) = fs;
  *reinterpret_cast<frag8*>(cg + off) = fc;
  *reinterpret_cast<frag8*>(pg + off) = fp;
}

// epilogue for N=256 GEMMs: bias (+relu) then store bf16 into LDS [32][stride]
__device__ __forceinline__ void epi4(const f4 (&acc)[2][4],
                                     const float* __restrict__ bias, bool relu,
                                     short* __restrict__ dst, int stride,
                                     int wv, int m15, int q)
{
  #pragma unroll
  for (int c = 0; c < 4; ++c) {
    int col = wv * 64 + c * 16 + m15;
    float bv = bias[col];
    #pragma unroll
    for (int t = 0; t < 2; ++t) {
      #pragma unroll
      for (int r = 0; r < 4; ++r) {
        float x = acc[t][c][r] + bv;
        if (relu) x = fmaxf(x, 0.f);
        dst[(t * 16 + q * 4 + r) * stride + col] = f2bf(x);
      }
    }
  }
}

__global__ __launch_bounds__(256, 2) void k_main(
    const short* __restrict__ sg, const short* __restrict__ cg,
    const short* __restrict__ pg,
    const short* __restrict__ w1p,  const short* __restrict__ w2p,
    const short* __restrict__ dw1p, const short* __restrict__ dw2p,
    const short* __restrict__ fw1p, const short* __restrict__ fw2p,
    const float* __restrict__ cm_b1, const float* __restrict__ cm_b2,
    const float* __restrict__ df_b1, const float* __restrict__ df_b2,
    const float* __restrict__ fu_b1, const float* __restrict__ fu_b2,
    const float* __restrict__ ln_g,  const float* __restrict__ ln_b,
    const float* __restrict__ hdrf,  float* __restrict__ out)
{
  __shared__ short sCF[32 * 256];   // 16KB  cross_f  (later: LN reduce buf)
  __shared__ short sDF[32 * 256];   // 16KB  diff_f
  __shared__ short sXY[32 * 512];   // 32KB  X1/X2 (first half) then Y

  const int tid  = threadIdx.x;
  const int wv   = tid >> 6;        // wave 0..3 -> col strip
  const int lane = tid & 63;
  const int m15  = lane & 15;
  const int q    = lane >> 4;
  const int blk  = blockIdx.x;
  const int t0   = blk * 2, t1 = blk * 2 + 1;   // global 16-row tile indices
  const f4 fz = {0.f, 0.f, 0.f, 0.f};

  // ---------------- GEMM1: X1 = relu([s|c|s*c] @ cm_w1 + b1) ----------------
  {
    f4 acc[2][4];
    #pragma unroll
    for (int t = 0; t < 2; ++t) {
      #pragma unroll
      for (int c = 0; c < 4; ++c) acc[t][c] = fz;
    }
    auto seg = [&](const short* __restrict__ A, int kb) {
      #pragma unroll
      for (int kk = 0; kk < 8; ++kk) {
        frag8 a0 = ldg8(A + ((size_t)(t0 * 8 + kk) * 64 + lane) * 8);
        frag8 a1 = ldg8(A + ((size_t)(t1 * 8 + kk) * 64 + lane) * 8);
        #pragma unroll
        for (int c = 0; c < 4; ++c) {
          frag8 b = ldg8(w1p + ((size_t)((wv * 4 + c) * 24 + kb + kk) * 64 + lane) * 8);
          acc[0][c] = MFMA16(a0, b, acc[0][c]);
          acc[1][c] = MFMA16(a1, b, acc[1][c]);
        }
      }
    };
    seg(sg, 0); seg(cg, 8); seg(pg, 16);
    epi4(acc, cm_b1, true, sXY, 256, wv, m15, q);
  }
  __syncthreads();

  // ---------------- GEMM2: cross_f = X1 @ cm_w2 + b2 ----------------
  {
    f4 acc[2][4];
    #pragma unroll
    for (int t = 0; t < 2; ++t) {
      #pragma unroll
      for (int c = 0; c < 4; ++c) acc[t][c] = fz;
    }
    #pragma unroll
    for (int kk = 0; kk < 8; ++kk) {
      frag8 a0 = *reinterpret_cast<const frag8*>(&sXY[(m15) * 256 + kk * 32 + q * 8]);
      frag8 a1 = *reinterpret_cast<const frag8*>(&sXY[(16 + m15) * 256 + kk * 32 + q * 8]);
      #pragma unroll
      for (int c = 0; c < 4; ++c) {
        frag8 b = ldg8(w2p + ((size_t)((wv * 4 + c) * 8 + kk) * 64 + lane) * 8);
        acc[0][c] = MFMA16(a0, b, acc[0][c]);
        acc[1][c] = MFMA16(a1, b, acc[1][c]);
      }
    }
    epi4(acc, cm_b2, false, sCF, 256, wv, m15, q);
  }
  __syncthreads();

  // ---------- GEMMd1: X2 = relu([d | |d|] @ df_w1 + b1), d = s - c ----------
  {
    f4 acc[2][4];
    #pragma unroll
    for (int t = 0; t < 2; ++t) {
      #pragma unroll
      for (int c = 0; c < 4; ++c) acc[t][c] = fz;
    }
    #pragma unroll
    for (int kk = 0; kk < 8; ++kk) {
      frag8 s0 = ldg8(sg + ((size_t)(t0 * 8 + kk) * 64 + lane) * 8);
      frag8 s1 = ldg8(sg + ((size_t)(t1 * 8 + kk) * 64 + lane) * 8);
      frag8 c0 = ldg8(cg + ((size_t)(t0 * 8 + kk) * 64 + lane) * 8);
      frag8 c1 = ldg8(cg + ((size_t)(t1 * 8 + kk) * 64 + lane) * 8);
      frag8 d0, d1;
      #pragma unroll
      for (int j = 0; j < 8; ++j) {
        d0[j] = f2bf(bf2f(s0[j]) - bf2f(c0[j]));
        d1[j] = f2bf(bf2f(s1[j]) - bf2f(c1[j]));
      }
      i4 ai0 = __builtin_bit_cast(i4, d0);
      i4 ai1 = __builtin_bit_cast(i4, d1);
      #pragma unroll
      for (int jj = 0; jj < 4; ++jj) { ai0[jj] &= 0x7FFF7FFF; ai1[jj] &= 0x7FFF7FFF; }
      frag8 e0 = __builtin_bit_cast(frag8, ai0);   // |d| : sign-bit clear
      frag8 e1 = __builtin_bit_cast(frag8, ai1);
      #pragma unroll
      for (int c = 0; c < 4; ++c) {
        frag8 b0 = ldg8(dw1p + ((size_t)((wv * 4 + c) * 16 + kk) * 64 + lane) * 8);
        acc[0][c] = MFMA16(d0, b0, acc[0][c]);
        acc[1][c] = MFMA16(d1, b0, acc[1][c]);
        frag8 b1 = ldg8(dw1p + ((size_t)((wv * 4 + c) * 16 + 8 + kk) * 64 + lane) * 8);
        acc[0][c] = MFMA16(e0, b1, acc[0][c]);
        acc[1][c] = MFMA16(e1, b1, acc[1][c]);
      }
    }
    epi4(acc, df_b1, true, sXY, 256, wv, m15, q);
  }
  __syncthreads();

  // ---------------- GEMMd2: diff_f = X2 @ df_w2 + b2 ----------------
  {
    f4 acc[2][4];
    #pragma unroll
    for (int t = 0; t < 2; ++t) {
      #pragma unroll
      for (int c = 0; c < 4; ++c) acc[t][c] = fz;
    }
    #pragma unroll
    for (int kk = 0; kk < 8; ++kk) {
      frag8 a0 = *reinterpret_cast<const frag8*>(&sXY[(m15) * 256 + kk * 32 + q * 8]);
      frag8 a1 = *reinterpret_cast<const frag8*>(&sXY[(16 + m15) * 256 + kk * 32 + q * 8]);
      #pragma unroll
      for (int c = 0; c < 4; ++c) {
        frag8 b = ldg8(dw2p + ((size_t)((wv * 4 + c) * 8 + kk) * 64 + lane) * 8);
        acc[0][c] = MFMA16(a0, b, acc[0][c]);
        acc[1][c] = MFMA16(a1, b, acc[1][c]);
      }
    }
    epi4(acc, df_b2, false, sDF, 256, wv, m15, q);
  }
  __syncthreads();

  // ------- GEMM3a: Y = relu([cross_f|diff_f|prod] @ fu_w1 + b1), N=512 -------
  {
    f4 acc[2][8];
    #pragma unroll
    for (int t = 0; t < 2; ++t) {
      #pragma unroll
      for (int c = 0; c < 8; ++c) acc[t][c] = fz;
    }
    auto segL = [&](const short* __restrict__ Abuf, int kb) {
      #pragma unroll
      for (int kk = 0; kk < 8; ++kk) {
        frag8 a0 = *reinterpret_cast<const frag8*>(&Abuf[(m15) * 256 + kk * 32 + q * 8]);
        frag8 a1 = *reinterpret_cast<const frag8*>(&Abuf[(16 + m15) * 256 + kk * 32 + q * 8]);
        #pragma unroll
        for (int c = 0; c < 8; ++c) {
          frag8 b = ldg8(fw1p + ((size_t)((wv * 8 + c) * 24 + kb + kk) * 64 + lane) * 8);
          acc[0][c] = MFMA16(a0, b, acc[0][c]);
          acc[1][c] = MFMA16(a1, b, acc[1][c]);
        }
      }
    };
    segL(sCF, 0); segL(sDF, 8);
    #pragma unroll
    for (int kk = 0; kk < 8; ++kk) {
      frag8 a0 = ldg8(pg + ((size_t)(t0 * 8 + kk) * 64 + lane) * 8);
      frag8 a1 = ldg8(pg + ((size_t)(t1 * 8 + kk) * 64 + lane) * 8);
      #pragma unroll
      for (int c = 0; c < 8; ++c) {
        frag8 b = ldg8(fw1p + ((size_t)((wv * 8 + c) * 24 + 16 + kk) * 64 + lane) * 8);
        acc[0][c] = MFMA16(a0, b, acc[0][c]);
        acc[1][c] = MFMA16(a1, b, acc[1][c]);
      }
    }
    #pragma unroll
    for (int c = 0; c < 8; ++c) {
      int col = wv * 128 + c * 16 + m15;
      float bv = fu_b1[col];
      #pragma unroll
      for (int t = 0; t < 2; ++t) {
        #pragma unroll
        for (int r = 0; r < 4; ++r) {
          float x = fmaxf(acc[t][c][r] + bv, 0.f);
          sXY[(t * 16 + q * 4 + r) * 512 + col] = f2bf(x);
        }
      }
    }
  }
  __syncthreads();

  // ------- GEMM3b: fused = Y @ fu_w2 + b2 ; LayerNorm ; weighted sum -------
  {
    f4 acc[2][4];
    #pragma unroll
    for (int t = 0; t < 2; ++t) {
      #pragma unroll
      for (int c = 0; c < 4; ++c) acc[t][c] = fz;
    }
    #pragma unroll
    for (int kk = 0; kk < 16; ++kk) {
      frag8 a0 = *reinterpret_cast<const frag8*>(&sXY[(m15) * 512 + kk * 32 + q * 8]);
      frag8 a1 = *reinterpret_cast<const frag8*>(&sXY[(16 + m15) * 512 + kk * 32 + q * 8]);
      #pragma unroll
      for (int c = 0; c < 4; ++c) {
        frag8 b = ldg8(fw2p + ((size_t)((wv * 4 + c) * 16 + kk) * 64 + lane) * 8);
        acc[0][c] = MFMA16(a0, b, acc[0][c]);
        acc[1][c] = MFMA16(a1, b, acc[1][c]);
      }
    }
    // fused values (f32): vals[t][c][r] at row = t*16 + q*4 + r, col = wv*64+c*16+m15
    float vals[2][4][4];
    #pragma unroll
    for (int c = 0; c < 4; ++c) {
      int col = wv * 64 + c * 16 + m15;
      float bv = fu_b2[col];
      #pragma unroll
      for (int t = 0; t < 2; ++t) {
        #pragma unroll
        for (int r = 0; r < 4; ++r) vals[t][c][r] = acc[t][c][r] + bv;
      }
    }
    // LN: per-row sum/sumsq — in-lane over c, shfl over 16 col-lanes, LDS over waves
    float s1v[2][4], s2v[2][4];
    #pragma unroll
    for (int t = 0; t < 2; ++t) {
      #pragma unroll
      for (int r = 0; r < 4; ++r) {
        float a = 0.f, b = 0.f;
        #pragma unroll
        for (int c = 0; c < 4; ++c) { float v = vals[t][c][r]; a += v; b += v * v; }
        s1v[t][r] = a; s2v[t][r] = b;
      }
    }
    #pragma unroll
    for (int off = 8; off >= 1; off >>= 1) {
      #pragma unroll
      for (int t = 0; t < 2; ++t) {
        #pragma unroll
        for (int r = 0; r < 4; ++r) {
          s1v[t][r] += __shfl_xor(s1v[t][r], off, 64);
          s2v[t][r] += __shfl_xor(s2v[t][r], off, 64);
        }
      }
    }
    float* red = reinterpret_cast<float*>(sCF);   // sCF dead after GEMM3a
    if (m15 == 0) {
      #pragma unroll
      for (int t = 0; t < 2; ++t) {
        #pragma unroll
        for (int r = 0; r < 4; ++r) {
          int row = t * 16 + q * 4 + r;
          red[(row * 4 + wv) * 2 + 0] = s1v[t][r];
          red[(row * 4 + wv) * 2 + 1] = s2v[t][r];
        }
      }
    }
    __syncthreads();
    float mu[2][4], rs[2][4];
    #pragma unroll
    for (int t = 0; t < 2; ++t) {
      #pragma unroll
      for (int r = 0; r < 4; ++r) {
        int row = t * 16 + q * 4 + r;
        float S1 = 0.f, S2 = 0.f;
        #pragma unroll
        for (int w = 0; w < 4; ++w) {
          S1 += red[(row * 4 + w) * 2];
          S2 += red[(row * 4 + w) * 2 + 1];
        }
        float m_ = S1 * (1.0f / 256.0f);
        float v_ = S2 * (1.0f / 256.0f) - m_ * m_;
        mu[t][r] = m_;
        rs[t][r] = rsqrtf(v_ + 1e-5f);
      }
    }
    // weighted sum over topk slots: rows 4g..4g+3 are regs r of one lane
    float wts[4] = {hdrf[0], hdrf[1], hdrf[2], hdrf[3]};
    #pragma unroll
    for (int c = 0; c < 4; ++c) {
      int col = wv * 64 + c * 16 + m15;
      float gv = ln_g[col], bv = ln_b[col];
      #pragma unroll
      for (int t = 0; t < 2; ++t) {
        float o = 0.f;
        #pragma unroll
        for (int r = 0; r < 4; ++r) {
          float rel = (vals[t][c][r] - mu[t][r]) * rs[t][r] * gv + bv;
          o += wts[r] * rel;
        }
        out[((size_t)(blk * 8 + t * 4 + q)) * 256 + col] = o;
      }
    }
  }
}

extern "C" void kernel_launch(void* const* d_in, const int* in_sizes, int n_in,
                              void* d_out, int out_size, void* d_ws, size_t ws_size,
                              hipStream_t stream)
{
  (void)in_sizes; (void)n_in; (void)out_size; (void)ws_size;
  const float* sEnc  = (const float*)d_in[0];
  const float* cEnc  = (const float*)d_in[1];
  const float* ps    = (const float*)d_in[2];
  const float* temp  = (const float*)d_in[3];
  const float* cm_w1 = (const float*)d_in[4];
  const float* cm_b1 = (const float*)d_in[5];
  const float* cm_w2 = (const float*)d_in[6];
  const float* cm_b2 = (const float*)d_in[7];
  const float* df_w1 = (const float*)d_in[8];
  const float* df_b1 = (const float*)d_in[9];
  const float* df_w2 = (const float*)d_in[10];
  const float* df_b2 = (const float*)d_in[11];
  const float* fu_w1 = (const float*)d_in[12];
  const float* fu_b1 = (const float*)d_in[13];
  const float* fu_w2 = (const float*)d_in[14];
  const float* fu_b2 = (const float*)d_in[15];
  const float* ln_g  = (const float*)d_in[16];
  const float* ln_b  = (const float*)d_in[17];

  char*  ws   = (char*)d_ws;
  float* hdrf = (float*)ws;
  int*   hdri = (int*)ws;
  short* w1p  = (short*)(ws + 256);
  short* w2p  = (short*)(ws + 393472);
  short* dw1p = (short*)(ws + 524544);
  short* dw2p = (short*)(ws + 786688);
  short* fw1p = (short*)(ws + 917760);
  short* fw2p = (short*)(ws + 1704192);
  short* sg   = (short*)(ws + 2097152);
  short* cg   = sg + (size_t)33554432;
  short* pg   = cg + (size_t)33554432;
  float* out  = (float*)d_out;

  k_prep<<<481, 256, 0, stream>>>(ps, temp, cm_w1, cm_w2, df_w1, df_w2, fu_w1, fu_w2,
                                  w1p, w2p, dw1p, dw2p, fw1p, fw2p, hdrf, hdri);
  k_gather<<<16384, 256, 0, stream>>>(sEnc, cEnc, (const int*)ws, sg, cg, pg);
  k_main<<<4096, 256, 0, stream>>>(sg, cg, pg, w1p, w2p, dw1p, dw2p, fw1p, fw2p,
                                   cm_b1, cm_b2, df_b1, df_b2, fu_b1, fu_b2,
                                   ln_g, ln_b, hdrf, out);
}